// Round 14
// baseline (5527.942 us; speedup 1.0000x reference)
//
#include <hip/hip_runtime.h>

// LSTM: B=128, T=512, I=64, H=512, O=1, fp32 in/out.
// R13 = R10 core (LDS-staged quarters, ack+flag publish) with the WG-wide
// barrier removed from the per-step chain:
//  - per-wave narrowed producer poll: wave w polls only the 8 flags of
//    producer WGs 2w,2w+1 (exactly the producers of its kt=4w..4w+3)
//  - LDS chunk-flags (monotonic =t, parity-split) replace __syncthreads;
//    foreign chunks gated by ~30cy LDS polls instead of a full barrier
//  - own 4 kt MFMA directly from load registers (LDS roundtrip is identity
//    for the staging lane); foreign 12 kt from LDS in staggered group order
//  - projection partials: contention-free plain stores part[32][B][T]
// WAR safety: distance-2 transitive chain through producer flags covers both
// global slot reuse and LDS tile parity reuse (flags monotonic, no reset).

#define B_ 128
#define T_ 512
#define I_ 64
#define H_ 512

typedef __attribute__((ext_vector_type(8))) short short8;   // 8 bf16
typedef __attribute__((ext_vector_type(4))) float f32x4;
typedef __attribute__((ext_vector_type(4))) unsigned u32x4;

__device__ inline unsigned f2bf_u(float f) {
  union { float f; unsigned u; } v; v.f = f;
  return (v.u + 0x7fffu + ((v.u >> 16) & 1u)) >> 16;  // RNE
}
__device__ inline float bf2f(unsigned s) {
  union { unsigned u; float f; } v; v.u = s << 16; return v.f;
}
__device__ inline float sigm(float x) { return 1.0f / (1.0f + __expf(-x)); }
__device__ inline float tanh_(float x) { return 1.0f - 2.0f / (1.0f + __expf(2.0f * x)); }

#define WAITV(N)                                        \
  asm volatile("s_waitcnt vmcnt(" #N ")" ::: "memory"); \
  __builtin_amdgcn_sched_barrier(0)

// coherent 16B load at L3 point
#define HLOADQ(dst, base, OFF)                                            \
  asm volatile("global_load_dwordx4 %0, %1, off offset:" #OFF " sc0 sc1"  \
               : "=v"(dst) : "v"(base))

// x: read-only input, normal cached path
#define XLOADQ(dst, base, OFF)                                            \
  asm volatile("global_load_dwordx4 %0, %1, off offset:" #OFF             \
               : "=v"(dst) : "v"(base))

// coherent 8B store at L3 point (4 lanes = contiguous 32B)
#define HSTORED2(base, v64)                                               \
  asm volatile("global_store_dwordx2 %0, %1, off sc0 sc1"                 \
               :: "v"(base), "v"(v64) : "memory")

template <int PLAIN>
__global__ __launch_bounds__(256, 1) void lstm_kernel(
    const float* __restrict__ x,    // [B,T,I]
    const float* __restrict__ Wih,  // [4H,I]
    const float* __restrict__ Whh,  // [4H,H]
    const float* __restrict__ bih,  // [4H]
    const float* __restrict__ bhh,  // [4H]
    const float* __restrict__ Who,  // [1,H]
    float* __restrict__ part,       // PLAIN: [32][B][T]; else [8][B][T] atomic
    unsigned short* __restrict__ hbuf,  // 2 bufs x (hi[B][H], lo[B][H]) bf16
    unsigned* __restrict__ flags)       // 8 bg x 32 per-wave flags
{
  const int bid = blockIdx.x;
  const int jg = bid >> 3;      // 0..7  hidden group (64 j)
  const int bg = bid & 7;       // 0..7  batch group (16 b)
  const int tid = threadIdx.x;
  const int w = tid >> 6;       // wave 0..3
  const int l = tid & 63;
  const int l16 = l & 15;
  const int lk = l >> 4;        // 0..3
  const int b = bg * 16 + l16;

  // ---- resident weights: bf16 A-frags, 4 M-tiles/wave ----
  short8 a_hh[4][16], a_ih[4][2];
  float bias[4][4], who[4];
#pragma unroll
  for (int m = 0; m < 4; ++m) {
    const int rowA = w * 64 + m * 16 + l16;                    // WG row = jl*4+gate
    const int grow = (rowA & 3) * 512 + jg * 64 + (rowA >> 2); // global gate row
#pragma unroll
    for (int kt = 0; kt < 16; ++kt) {
      const float* p = Whh + (size_t)grow * H_ + kt * 32 + lk * 8;
      short8 s;
#pragma unroll
      for (int e = 0; e < 8; ++e) s[e] = (short)f2bf_u(p[e]);
      a_hh[m][kt] = s;
    }
#pragma unroll
    for (int kt = 0; kt < 2; ++kt) {
      const float* p = Wih + (size_t)grow * I_ + kt * 32 + lk * 8;
      short8 s;
#pragma unroll
      for (int e = 0; e < 8; ++e) s[e] = (short)f2bf_u(p[e]);
      a_ih[m][kt] = s;
    }
    const int jm = jg * 64 + w * 16 + m * 4 + lk;
#pragma unroll
    for (int g = 0; g < 4; ++g) bias[m][g] = bih[g * 512 + jm] + bhh[g * 512 + jm];
    who[m] = Who[jm];
  }

  // LDS h-tile: [parity][plane][b][512 j], XOR-swizzled 16B granules (R10).
  __shared__ unsigned short hlds[2][2][16][512];   // 64 KiB
  __shared__ int lflag[2][4];                      // [parity][stager wave]
#define HOFS(pl, bb, kt) (((((pl) * 16 + (bb)) * 512) + (kt) * 32 + lk * 8) ^ (((bb) & 7) << 3))

  if (tid < 8) ((int*)lflag)[tid] = 0;
  __syncthreads();   // once, before the loop

  unsigned short* const hb0 = hbuf;
  unsigned short* const hb1 = hbuf + 2 * B_ * H_;
  unsigned* const fbase = flags + (size_t)bg * 32;
  unsigned* const myflag = fbase + (jg * 4 + w);
  const float* const xrow = x + (size_t)b * (T_ * I_);

  float c[4] = {0.f, 0.f, 0.f, 0.f};
  f32x4 xf0, xf1, xf2, xf3;
  {
    const float* xb = xrow + lk * 8;   // t = 0
    XLOADQ(xf0, xb, 0);   XLOADQ(xf1, xb, 16);
    XLOADQ(xf2, xb, 128); XLOADQ(xf3, xb, 144);
    WAITV(0);
  }

  for (int t = 0; t < T_; ++t) {
    const int pr = t & 1;
    const unsigned short* hp = pr ? hb1 : hb0;   // slot holding h(t-1)
    unsigned short* hn       = pr ? hb0 : hb1;   // slot for h(t)
    unsigned short* const hldsF = &hlds[pr][0][0][0];

    f32x4 acc[4][2];
#pragma unroll
    for (int m = 0; m < 4; ++m) {
      acc[m][0] = (f32x4){0.f, 0.f, 0.f, 0.f};
      acc[m][1] = (f32x4){0.f, 0.f, 0.f, 0.f};
    }

    // ---- x projection from prefetched regs (pure VALU+MFMA) ----
#pragma unroll
    for (int kt = 0; kt < 2; ++kt) {
      f32x4 va = kt ? xf2 : xf0;
      f32x4 vb = kt ? xf3 : xf1;
      float v[8] = {va[0], va[1], va[2], va[3], vb[0], vb[1], vb[2], vb[3]};
      short8 xhi, xlo;
#pragma unroll
      for (int e = 0; e < 8; ++e) {
        unsigned hb = f2bf_u(v[e]);
        xhi[e] = (short)hb;
        xlo[e] = (short)f2bf_u(v[e] - bf2f(hb));
      }
#pragma unroll
      for (int m = 0; m < 4; ++m) {
        acc[m][0] = __builtin_amdgcn_mfma_f32_16x16x32_bf16(a_ih[m][kt], xhi, acc[m][0], 0, 0, 0);
        acc[m][1] = __builtin_amdgcn_mfma_f32_16x16x32_bf16(a_ih[m][kt], xlo, acc[m][1], 0, 0, 0);
      }
    }

    if (t > 0) {
      // ---- narrowed detect: poll ONLY this wave's 8 producer flags
      //      (WGs 2w, 2w+1 = producers of kt 4w..4w+3) ----
      {
        const unsigned* fp = fbase + 8 * w + (l & 7);
        for (;;) {
          unsigned f = __hip_atomic_load(fp, __ATOMIC_RELAXED, __HIP_MEMORY_SCOPE_AGENT);
          if (__all(f >= (unsigned)t)) break;
        }
      }
      __builtin_amdgcn_fence(__ATOMIC_ACQUIRE, "workgroup");
      __builtin_amdgcn_sched_barrier(0);

      // ---- this wave's kt-quarter: 8x16B loads + x(t+1) issue ----
      u32x4 qh[4], ql[4];
      const unsigned short* phh = hp + (size_t)b * H_ + w * 128 + lk * 8;
      const unsigned short* pll = phh + (size_t)(B_ * H_);
      HLOADQ(qh[0], phh, 0);   HLOADQ(qh[1], phh, 64);
      HLOADQ(qh[2], phh, 128); HLOADQ(qh[3], phh, 192);
      HLOADQ(ql[0], pll, 0);   HLOADQ(ql[1], pll, 64);
      HLOADQ(ql[2], pll, 128); HLOADQ(ql[3], pll, 192);
      {
        const int tn = (t + 1 < T_) ? t + 1 : t;
        const float* xb = xrow + tn * I_ + lk * 8;
        XLOADQ(xf0, xb, 0);   XLOADQ(xf1, xb, 16);
        XLOADQ(xf2, xb, 128); XLOADQ(xf3, xb, 144);
      }
      WAITV(4);   // 8 h-quarter loads done; 4 x loads in flight

      // ---- stage own chunks, release LDS chunk-flag ----
#pragma unroll
      for (int i = 0; i < 4; ++i) {
        *(u32x4*)&hldsF[HOFS(0, l16, 4 * w + i)] = qh[i];
        *(u32x4*)&hldsF[HOFS(1, l16, 4 * w + i)] = ql[i];
      }
      asm volatile("s_waitcnt lgkmcnt(0)" ::: "memory");
      __builtin_amdgcn_sched_barrier(0);
      *(volatile int*)&lflag[pr][w] = t;

      // ---- own 4 kt straight from registers (no LDS roundtrip) ----
#pragma unroll
      for (int i = 0; i < 4; ++i) {
        const int kt = 4 * w + i;
        union { u32x4 u; short8 s; } uh, ul;
        uh.u = qh[i]; ul.u = ql[i];
#pragma unroll
        for (int m = 0; m < 4; ++m) {
          acc[m][0] = __builtin_amdgcn_mfma_f32_16x16x32_bf16(a_hh[m][kt], uh.s, acc[m][0], 0, 0, 0);
          acc[m][1] = __builtin_amdgcn_mfma_f32_16x16x32_bf16(a_hh[m][kt], ul.s, acc[m][1], 0, 0, 0);
        }
      }

      // ---- foreign 12 kt: gate on LDS chunk-flags, staggered order ----
#pragma unroll
      for (int g = 1; g < 4; ++g) {
        const int w2 = (w + g) & 3;
        while (*(volatile const int*)&lflag[pr][w2] < t) {}
        __builtin_amdgcn_sched_barrier(0);
#pragma unroll
        for (int i = 0; i < 4; ++i) {
          const int kt = 4 * w2 + i;
          short8 fh = *(const short8*)&hldsF[HOFS(0, l16, kt)];
          short8 fl = *(const short8*)&hldsF[HOFS(1, l16, kt)];
#pragma unroll
          for (int m = 0; m < 4; ++m) {
            acc[m][0] = __builtin_amdgcn_mfma_f32_16x16x32_bf16(a_hh[m][kt], fh, acc[m][0], 0, 0, 0);
            acc[m][1] = __builtin_amdgcn_mfma_f32_16x16x32_bf16(a_hh[m][kt], fl, acc[m][1], 0, 0, 0);
          }
        }
      }
    } else {
      // t=0: no h term; just issue x(1) prefetch
      const float* xb = xrow + I_ + lk * 8;
      XLOADQ(xf0, xb, 0);   XLOADQ(xf1, xb, 16);
      XLOADQ(xf2, xb, 128); XLOADQ(xf3, xb, 144);
    }

    // ---- pointwise (lane-local: 4 cells x 4 gates) + pack ----
    float p = 0.f;
    unsigned wd[4];           // packed (hi | lo<<16) per m
#pragma unroll
    for (int m = 0; m < 4; ++m) {
      float gi = sigm(acc[m][0].x + acc[m][1].x + bias[m][0]);
      float gf = sigm(acc[m][0].y + acc[m][1].y + bias[m][1]);
      float gg = tanh_(acc[m][0].z + acc[m][1].z + bias[m][2]);
      float go = sigm(acc[m][0].w + acc[m][1].w + bias[m][3]);
      c[m] = gf * c[m] + gi * gg;
      float hv = go * tanh_(c[m]);
      p += hv * who[m];
      unsigned hb = f2bf_u(hv);
      wd[m] = hb | (f2bf_u(hv - bf2f(hb)) << 16);
    }

    // ---- in-register 4x4 transpose across lk (lanes ^16, ^32) ----
    {
      unsigned r0[4], r1[4];
#pragma unroll
      for (int m = 0; m < 4; ++m) r0[m] = __shfl_xor(wd[m], 16);
#pragma unroll
      for (int m = 0; m < 4; ++m) if ((m ^ lk) & 1) wd[m] = r0[m ^ 1];
#pragma unroll
      for (int m = 0; m < 4; ++m) r1[m] = __shfl_xor(wd[m], 32);
#pragma unroll
      for (int m = 0; m < 4; ++m) if ((m ^ lk) & 2) wd[m] = r1[m ^ 2];
    }

    // ---- publish: coalesced 8B stores per plane ----
    {
      unsigned hi01 = (wd[0] & 0xffffu) | (wd[1] << 16);
      unsigned hi23 = (wd[2] & 0xffffu) | (wd[3] << 16);
      unsigned lo01 = (wd[0] >> 16) | (wd[1] & 0xffff0000u);
      unsigned lo23 = (wd[2] >> 16) | (wd[3] & 0xffff0000u);
      unsigned long long hiq = (unsigned long long)hi01 | ((unsigned long long)hi23 << 32);
      unsigned long long loq = (unsigned long long)lo01 | ((unsigned long long)lo23 << 32);
      unsigned short* ph = hn + (size_t)b * H_ + jg * 64 + w * 16 + lk * 4;
      HSTORED2(ph, hiq);
      HSTORED2(ph + B_ * H_, loq);
    }

    // projection reduce (VALU-only) overlaps the ack
    p += __shfl_xor(p, 16);
    p += __shfl_xor(p, 32);          // sum over this wave's 16 j

    WAITV(0);  // ack: h stores committed at L3 (also drains x(t+1))
    if (l == 0)
      __hip_atomic_store(myflag, (unsigned)(t + 1),
                         __ATOMIC_RELAXED, __HIP_MEMORY_SCOPE_AGENT);

    // ---- projection partial: contention-free plain store or atomic ----
    if (l < 16) {
      if constexpr (PLAIN != 0)
        part[(((size_t)jg * 4 + w) * B_ + b) * T_ + t] = p;
      else
        atomicAdd(part + ((size_t)jg * B_ + b) * T_ + t, p);
    }
  }
#undef HOFS
}

template <int NP>
__global__ __launch_bounds__(256) void reduce_out(const float* __restrict__ part,
                                                  const float* __restrict__ b_ho,
                                                  float* __restrict__ out) {
  int i = blockIdx.x * blockDim.x + threadIdx.x;
  if (i < B_ * T_) {
    float s = b_ho[0];
#pragma unroll
    for (int g = 0; g < NP; ++g) s += part[(size_t)g * B_ * T_ + i];
    out[i] = s;
  }
}

extern "C" void kernel_launch(void* const* d_in, const int* in_sizes, int n_in,
                              void* d_out, int out_size, void* d_ws, size_t ws_size,
                              hipStream_t stream) {
  (void)in_sizes; (void)n_in; (void)out_size;
  const float* x   = (const float*)d_in[0];
  const float* Wih = (const float*)d_in[1];
  const float* Whh = (const float*)d_in[2];
  const float* bih = (const float*)d_in[3];
  const float* bhh = (const float*)d_in[4];
  const float* Who = (const float*)d_in[5];
  const float* bho = (const float*)d_in[6];
  float* out = (float*)d_out;

  unsigned short* hbuf = (unsigned short*)d_ws;
  const size_t hbytes = (size_t)2 * 2 * B_ * H_ * sizeof(unsigned short);  // 512KB
  float* part = (float*)((char*)d_ws + hbytes);

  const size_t pbytes32 = (size_t)32 * B_ * T_ * sizeof(float);  // 8MB
  const size_t pbytes8  = (size_t)8 * B_ * T_ * sizeof(float);   // 2MB
  const size_t fbytes   = 8 * 32 * sizeof(unsigned);

  if (ws_size >= hbytes + pbytes32 + fbytes) {
    unsigned* flags = (unsigned*)((char*)d_ws + hbytes + pbytes32);
    hipMemsetAsync(flags, 0, fbytes, stream);   // part fully overwritten
    lstm_kernel<1><<<dim3(64), dim3(256), 0, stream>>>(x, Wih, Whh, bih, bhh,
                                                       Who, part, hbuf, flags);
    reduce_out<32><<<(B_ * T_ + 255) / 256, 256, 0, stream>>>(part, bho, out);
  } else {
    unsigned* flags = (unsigned*)((char*)d_ws + hbytes + pbytes8);
    hipMemsetAsync(part, 0, pbytes8 + fbytes, stream);
    lstm_kernel<0><<<dim3(64), dim3(256), 0, stream>>>(x, Wih, Whh, bih, bhh,
                                                       Who, part, hbuf, flags);
    reduce_out<8><<<(B_ * T_ + 255) / 256, 256, 0, stream>>>(part, bho, out);
  }
}

// Round 15
// 2590.017 us; speedup vs baseline: 2.1343x; 2.1343x over previous
//
#include <hip/hip_runtime.h>

// LSTM: B=128, T=512, I=64, H=512, O=1, fp32 in/out.
// R14 = R10 champion, byte-identical core, + ONE isolated change:
//   projection partials via contention-free plain stores part[32][B][T]
//   (R12-validated), issued BEFORE the ack WAITV(0) so the partial-store ack
//   overlaps the h-store ack and the next step's flag-poll FIFO stays clean
//   (R10's after-flag atomicAdd put a contended L3 RMW in the poll path).
// Core (R10-proven): 64 WGs = 8 jg x 8 bg; weights resident as bf16 A-frags;
// per-wave flags (relaxed AGENT atomics); h via sc0 sc1 asm ops; each wave
// loads only its kt-quarter -> XOR-swizzled LDS -> all waves MFMA from LDS;
// producer = publish -> ack -> flag; consumer = poll 32 flags -> load.

#define B_ 128
#define T_ 512
#define I_ 64
#define H_ 512

typedef __attribute__((ext_vector_type(8))) short short8;   // 8 bf16
typedef __attribute__((ext_vector_type(4))) float f32x4;
typedef __attribute__((ext_vector_type(4))) unsigned u32x4;

__device__ inline unsigned f2bf_u(float f) {
  union { float f; unsigned u; } v; v.f = f;
  return (v.u + 0x7fffu + ((v.u >> 16) & 1u)) >> 16;  // RNE
}
__device__ inline float bf2f(unsigned s) {
  union { unsigned u; float f; } v; v.u = s << 16; return v.f;
}
__device__ inline float sigm(float x) { return 1.0f / (1.0f + __expf(-x)); }
__device__ inline float tanh_(float x) { return 1.0f - 2.0f / (1.0f + __expf(2.0f * x)); }

#define WAITV(N)                                        \
  asm volatile("s_waitcnt vmcnt(" #N ")" ::: "memory"); \
  __builtin_amdgcn_sched_barrier(0)

// coherent 16B load at L3 point
#define HLOADQ(dst, base, OFF)                                            \
  asm volatile("global_load_dwordx4 %0, %1, off offset:" #OFF " sc0 sc1"  \
               : "=v"(dst) : "v"(base))

// x: read-only input, normal cached path
#define XLOADQ(dst, base, OFF)                                            \
  asm volatile("global_load_dwordx4 %0, %1, off offset:" #OFF             \
               : "=v"(dst) : "v"(base))

// coherent 8B store at L3 point (4 lanes = contiguous 32B)
#define HSTORED2(base, v64)                                               \
  asm volatile("global_store_dwordx2 %0, %1, off sc0 sc1"                 \
               :: "v"(base), "v"(v64) : "memory")

template <int PLAIN>
__global__ __launch_bounds__(256, 1) void lstm_kernel(
    const float* __restrict__ x,    // [B,T,I]
    const float* __restrict__ Wih,  // [4H,I]
    const float* __restrict__ Whh,  // [4H,H]
    const float* __restrict__ bih,  // [4H]
    const float* __restrict__ bhh,  // [4H]
    const float* __restrict__ Who,  // [1,H]
    float* __restrict__ part,       // PLAIN: [32][B][T]; else [8][B][T] atomic
    unsigned short* __restrict__ hbuf,  // 2 bufs x (hi[B][H], lo[B][H]) bf16
    unsigned* __restrict__ flags)       // 8 bg x 32 per-wave flags
{
  const int bid = blockIdx.x;
  const int jg = bid >> 3;      // 0..7  hidden group (64 j)
  const int bg = bid & 7;       // 0..7  batch group (16 b)
  const int tid = threadIdx.x;
  const int w = tid >> 6;       // wave 0..3
  const int l = tid & 63;
  const int l16 = l & 15;
  const int lk = l >> 4;        // 0..3
  const int b = bg * 16 + l16;

  // ---- resident weights: bf16 A-frags, 4 M-tiles/wave ----
  short8 a_hh[4][16], a_ih[4][2];
  float bias[4][4], who[4];
#pragma unroll
  for (int m = 0; m < 4; ++m) {
    const int rowA = w * 64 + m * 16 + l16;                    // WG row = jl*4+gate
    const int grow = (rowA & 3) * 512 + jg * 64 + (rowA >> 2); // global gate row
#pragma unroll
    for (int kt = 0; kt < 16; ++kt) {
      const float* p = Whh + (size_t)grow * H_ + kt * 32 + lk * 8;
      short8 s;
#pragma unroll
      for (int e = 0; e < 8; ++e) s[e] = (short)f2bf_u(p[e]);
      a_hh[m][kt] = s;
    }
#pragma unroll
    for (int kt = 0; kt < 2; ++kt) {
      const float* p = Wih + (size_t)grow * I_ + kt * 32 + lk * 8;
      short8 s;
#pragma unroll
      for (int e = 0; e < 8; ++e) s[e] = (short)f2bf_u(p[e]);
      a_ih[m][kt] = s;
    }
    const int jm = jg * 64 + w * 16 + m * 4 + lk;
#pragma unroll
    for (int g = 0; g < 4; ++g) bias[m][g] = bih[g * 512 + jm] + bhh[g * 512 + jm];
    who[m] = Who[jm];
  }

  // LDS h-tile: [parity][plane][b][512 j], XOR-swizzled 16B granules (R10).
  __shared__ unsigned short hlds[2][2][16][512];   // 64 KiB
#define HOFS(pl, bb, kt) (((((pl) * 16 + (bb)) * 512) + (kt) * 32 + lk * 8) ^ (((bb) & 7) << 3))

  unsigned short* const hb0 = hbuf;
  unsigned short* const hb1 = hbuf + 2 * B_ * H_;
  unsigned* const fbase = flags + (size_t)bg * 32;
  unsigned* const myflag = fbase + (jg * 4 + w);
  const float* const xrow = x + (size_t)b * (T_ * I_);

  float c[4] = {0.f, 0.f, 0.f, 0.f};
  f32x4 xf0, xf1, xf2, xf3;
  {
    const float* xb = xrow + lk * 8;   // t = 0
    XLOADQ(xf0, xb, 0);   XLOADQ(xf1, xb, 16);
    XLOADQ(xf2, xb, 128); XLOADQ(xf3, xb, 144);
    WAITV(0);
  }

  for (int t = 0; t < T_; ++t) {
    const int pr = t & 1;
    const unsigned short* hp = pr ? hb1 : hb0;   // slot holding h(t-1)
    unsigned short* hn       = pr ? hb0 : hb1;   // slot for h(t)
    unsigned short* const hldsF = &hlds[pr][0][0][0];

    f32x4 acc[4][2];
#pragma unroll
    for (int m = 0; m < 4; ++m) {
      acc[m][0] = (f32x4){0.f, 0.f, 0.f, 0.f};
      acc[m][1] = (f32x4){0.f, 0.f, 0.f, 0.f};
    }

    // ---- x projection from prefetched regs (pure VALU+MFMA) ----
#pragma unroll
    for (int kt = 0; kt < 2; ++kt) {
      f32x4 va = kt ? xf2 : xf0;
      f32x4 vb = kt ? xf3 : xf1;
      float v[8] = {va[0], va[1], va[2], va[3], vb[0], vb[1], vb[2], vb[3]};
      short8 xhi, xlo;
#pragma unroll
      for (int e = 0; e < 8; ++e) {
        unsigned hb = f2bf_u(v[e]);
        xhi[e] = (short)hb;
        xlo[e] = (short)f2bf_u(v[e] - bf2f(hb));
      }
#pragma unroll
      for (int m = 0; m < 4; ++m) {
        acc[m][0] = __builtin_amdgcn_mfma_f32_16x16x32_bf16(a_ih[m][kt], xhi, acc[m][0], 0, 0, 0);
        acc[m][1] = __builtin_amdgcn_mfma_f32_16x16x32_bf16(a_ih[m][kt], xlo, acc[m][1], 0, 0, 0);
      }
    }

    if (t > 0) {
      // ---- cheap detect: poll 32 per-wave flags ----
      {
        const unsigned* fp = fbase + (l & 31);
        for (;;) {
          unsigned f = __hip_atomic_load(fp, __ATOMIC_RELAXED, __HIP_MEMORY_SCOPE_AGENT);
          if (__all(f >= (unsigned)t)) break;
        }
      }
      __builtin_amdgcn_fence(__ATOMIC_ACQUIRE, "workgroup");
      __builtin_amdgcn_sched_barrier(0);

      // ---- this wave's kt-quarter: 8x16B global loads + x(t+1) issue ----
      u32x4 qh[4], ql[4];
      {
        const unsigned short* phh = hp + (size_t)b * H_ + w * 128 + lk * 8;
        const unsigned short* pll = phh + (size_t)(B_ * H_);
        HLOADQ(qh[0], phh, 0);   HLOADQ(qh[1], phh, 64);
        HLOADQ(qh[2], phh, 128); HLOADQ(qh[3], phh, 192);
        HLOADQ(ql[0], pll, 0);   HLOADQ(ql[1], pll, 64);
        HLOADQ(ql[2], pll, 128); HLOADQ(ql[3], pll, 192);
        const int tn = (t + 1 < T_) ? t + 1 : t;
        const float* xb = xrow + tn * I_ + lk * 8;
        XLOADQ(xf0, xb, 0);   XLOADQ(xf1, xb, 16);
        XLOADQ(xf2, xb, 128); XLOADQ(xf3, xb, 144);
      }
      WAITV(4);   // 8 h-quarter loads done; 4 x loads still in flight

      // ---- stage into swizzled LDS ----
#pragma unroll
      for (int i = 0; i < 4; ++i) {
        *(u32x4*)&hldsF[HOFS(0, l16, 4 * w + i)] = qh[i];
        *(u32x4*)&hldsF[HOFS(1, l16, 4 * w + i)] = ql[i];
      }
      __syncthreads();

      // ---- h recurrence: fragments from LDS (compiler pipelines lgkmcnt) ----
#pragma unroll
      for (int kt = 0; kt < 16; ++kt) {
        short8 fh = *(const short8*)&hldsF[HOFS(0, l16, kt)];
        short8 fl = *(const short8*)&hldsF[HOFS(1, l16, kt)];
#pragma unroll
        for (int m = 0; m < 4; ++m) {
          acc[m][0] = __builtin_amdgcn_mfma_f32_16x16x32_bf16(a_hh[m][kt], fh, acc[m][0], 0, 0, 0);
          acc[m][1] = __builtin_amdgcn_mfma_f32_16x16x32_bf16(a_hh[m][kt], fl, acc[m][1], 0, 0, 0);
        }
      }
    } else {
      // t=0: no h term; just issue x(1) prefetch
      const float* xb = xrow + I_ + lk * 8;
      XLOADQ(xf0, xb, 0);   XLOADQ(xf1, xb, 16);
      XLOADQ(xf2, xb, 128); XLOADQ(xf3, xb, 144);
    }

    // ---- pointwise (lane-local: 4 cells x 4 gates) + pack ----
    float p = 0.f;
    unsigned wd[4];           // packed (hi | lo<<16) per m
#pragma unroll
    for (int m = 0; m < 4; ++m) {
      float gi = sigm(acc[m][0].x + acc[m][1].x + bias[m][0]);
      float gf = sigm(acc[m][0].y + acc[m][1].y + bias[m][1]);
      float gg = tanh_(acc[m][0].z + acc[m][1].z + bias[m][2]);
      float go = sigm(acc[m][0].w + acc[m][1].w + bias[m][3]);
      c[m] = gf * c[m] + gi * gg;
      float hv = go * tanh_(c[m]);
      p += hv * who[m];
      unsigned hb = f2bf_u(hv);
      wd[m] = hb | (f2bf_u(hv - bf2f(hb)) << 16);
    }

    // ---- in-register 4x4 transpose across lk (lanes ^16, ^32) ----
    {
      unsigned r0[4], r1[4];
#pragma unroll
      for (int m = 0; m < 4; ++m) r0[m] = __shfl_xor(wd[m], 16);
#pragma unroll
      for (int m = 0; m < 4; ++m) if ((m ^ lk) & 1) wd[m] = r0[m ^ 1];
#pragma unroll
      for (int m = 0; m < 4; ++m) r1[m] = __shfl_xor(wd[m], 32);
#pragma unroll
      for (int m = 0; m < 4; ++m) if ((m ^ lk) & 2) wd[m] = r1[m ^ 2];
    }

    // ---- publish: coalesced 8B stores per plane (R7-proven) ----
    {
      unsigned hi01 = (wd[0] & 0xffffu) | (wd[1] << 16);
      unsigned hi23 = (wd[2] & 0xffffu) | (wd[3] << 16);
      unsigned lo01 = (wd[0] >> 16) | (wd[1] & 0xffff0000u);
      unsigned lo23 = (wd[2] >> 16) | (wd[3] & 0xffff0000u);
      unsigned long long hiq = (unsigned long long)hi01 | ((unsigned long long)hi23 << 32);
      unsigned long long loq = (unsigned long long)lo01 | ((unsigned long long)lo23 << 32);
      unsigned short* ph = hn + (size_t)b * H_ + jg * 64 + w * 16 + lk * 4;
      HSTORED2(ph, hiq);
      HSTORED2(ph + B_ * H_, loq);
    }

    // projection reduce (VALU-only) + plain partial store BEFORE the ack:
    // its ack overlaps the h-store ack; next step's poll FIFO stays clean.
    p += __shfl_xor(p, 16);
    p += __shfl_xor(p, 32);          // sum over this wave's 16 j
    if constexpr (PLAIN != 0) {
      if (l < 16)
        part[(((size_t)jg * 4 + w) * B_ + b) * T_ + t] = p;
    }

    WAITV(0);  // ack: h stores (+ partial store) committed; x(t+1) regs ready
    if (l == 0)
      __hip_atomic_store(myflag, (unsigned)(t + 1),
                         __ATOMIC_RELAXED, __HIP_MEMORY_SCOPE_AGENT);

    if constexpr (PLAIN == 0) {
      if (l < 16) atomicAdd(part + ((size_t)jg * B_ + b) * T_ + t, p);
    }
  }
#undef HOFS
}

template <int NP>
__global__ __launch_bounds__(256) void reduce_out(const float* __restrict__ part,
                                                  const float* __restrict__ b_ho,
                                                  float* __restrict__ out) {
  int i = blockIdx.x * blockDim.x + threadIdx.x;
  if (i < B_ * T_) {
    float s = b_ho[0];
#pragma unroll
    for (int g = 0; g < NP; ++g) s += part[(size_t)g * B_ * T_ + i];
    out[i] = s;
  }
}

extern "C" void kernel_launch(void* const* d_in, const int* in_sizes, int n_in,
                              void* d_out, int out_size, void* d_ws, size_t ws_size,
                              hipStream_t stream) {
  (void)in_sizes; (void)n_in; (void)out_size;
  const float* x   = (const float*)d_in[0];
  const float* Wih = (const float*)d_in[1];
  const float* Whh = (const float*)d_in[2];
  const float* bih = (const float*)d_in[3];
  const float* bhh = (const float*)d_in[4];
  const float* Who = (const float*)d_in[5];
  const float* bho = (const float*)d_in[6];
  float* out = (float*)d_out;

  unsigned short* hbuf = (unsigned short*)d_ws;
  const size_t hbytes = (size_t)2 * 2 * B_ * H_ * sizeof(unsigned short);  // 512KB
  float* part = (float*)((char*)d_ws + hbytes);

  const size_t pbytes32 = (size_t)32 * B_ * T_ * sizeof(float);  // 8MB
  const size_t pbytes8  = (size_t)8 * B_ * T_ * sizeof(float);   // 2MB
  const size_t fbytes   = 8 * 32 * sizeof(unsigned);

  if (ws_size >= hbytes + pbytes32 + fbytes) {
    unsigned* flags = (unsigned*)((char*)d_ws + hbytes + pbytes32);
    hipMemsetAsync(flags, 0, fbytes, stream);   // part fully overwritten
    lstm_kernel<1><<<dim3(64), dim3(256), 0, stream>>>(x, Wih, Whh, bih, bhh,
                                                       Who, part, hbuf, flags);
    reduce_out<32><<<(B_ * T_ + 255) / 256, 256, 0, stream>>>(part, bho, out);
  } else {
    unsigned* flags = (unsigned*)((char*)d_ws + hbytes + pbytes8);
    hipMemsetAsync(part, 0, pbytes8 + fbytes, stream);
    lstm_kernel<0><<<dim3(64), dim3(256), 0, stream>>>(x, Wih, Whh, bih, bhh,
                                                       Who, part, hbuf, flags);
    reduce_out<8><<<(B_ * T_ + 255) / 256, 256, 0, stream>>>(part, bho, out);
  }
}

// Round 16
// 2246.209 us; speedup vs baseline: 2.4610x; 1.1531x over previous
//
#include <hip/hip_runtime.h>

// LSTM: B=128, T=512, I=64, H=512, O=1, fp32 in/out.
// R15 = R10/R14 core with the sync chain collapsed into the data:
//   NO ack, NO flags. Producer publishes tagged granules (R11's proven
//   4-bit epoch tags, lk==0 lanes) fire-and-forget. Consumer's poll IS the
//   quarter load: retry { 8x16B sc0sc1 loads -> vmcnt(0) -> tag validate }.
//   Fresh iteration leaves data in registers (commit+detect+load = ~2 RTs
//   instead of ack+flag+detect+load = ~4 RTs).
// WAR safety: transitive through the WG barrier — a producer reaches its
// h(t+1) stores only after all 32 waves of the bg published h(t), which
// follows their validated consumption of h(t-1). Torn granules (8B halves
// from different epochs) are caught by per-half header tags in all
// reachable interleavings. Stale/poison/prev-replay tags mismatch at t=1.
// Projection partials: contention-free plain stores part[32][B][T] (R14).

#define B_ 128
#define T_ 512
#define I_ 64
#define H_ 512

typedef __attribute__((ext_vector_type(8))) short short8;   // 8 bf16
typedef __attribute__((ext_vector_type(4))) float f32x4;
typedef __attribute__((ext_vector_type(4))) unsigned u32x4;

__device__ inline unsigned f2bf_u(float f) {
  union { float f; unsigned u; } v; v.f = f;
  return (v.u + 0x7fffu + ((v.u >> 16) & 1u)) >> 16;  // RNE
}
__device__ inline float bf2f(unsigned s) {
  union { unsigned u; float f; } v; v.u = s << 16; return v.f;
}
__device__ inline float sigm(float x) { return 1.0f / (1.0f + __expf(-x)); }
__device__ inline float tanh_(float x) { return 1.0f - 2.0f / (1.0f + __expf(2.0f * x)); }

#define WAITV(N)                                        \
  asm volatile("s_waitcnt vmcnt(" #N ")" ::: "memory"); \
  __builtin_amdgcn_sched_barrier(0)

// coherent 16B load at L3 point
#define HLOADQ(dst, base, OFF)                                            \
  asm volatile("global_load_dwordx4 %0, %1, off offset:" #OFF " sc0 sc1"  \
               : "=v"(dst) : "v"(base))

// x: read-only input, normal cached path
#define XLOADQ(dst, base, OFF)                                            \
  asm volatile("global_load_dwordx4 %0, %1, off offset:" #OFF             \
               : "=v"(dst) : "v"(base))

// coherent 8B store at L3 point (4 lanes = contiguous 32B)
#define HSTORED2(base, v64)                                               \
  asm volatile("global_store_dwordx2 %0, %1, off sc0 sc1"                 \
               :: "v"(base), "v"(v64) : "memory")

template <int PLAIN>
__global__ __launch_bounds__(256, 1) void lstm_kernel(
    const float* __restrict__ x,    // [B,T,I]
    const float* __restrict__ Wih,  // [4H,I]
    const float* __restrict__ Whh,  // [4H,H]
    const float* __restrict__ bih,  // [4H]
    const float* __restrict__ bhh,  // [4H]
    const float* __restrict__ Who,  // [1,H]
    float* __restrict__ part,       // PLAIN: [32][B][T]; else [8][B][T] atomic
    unsigned short* __restrict__ hbuf)  // 2 bufs x (hi[B][H], lo[B][H]) bf16
{
  const int bid = blockIdx.x;
  const int jg = bid >> 3;      // 0..7  hidden group (64 j)
  const int bg = bid & 7;       // 0..7  batch group (16 b)
  const int tid = threadIdx.x;
  const int w = tid >> 6;       // wave 0..3
  const int l = tid & 63;
  const int l16 = l & 15;
  const int lk = l >> 4;        // 0..3
  const int b = bg * 16 + l16;

  // ---- resident weights: bf16 A-frags, 4 M-tiles/wave ----
  short8 a_hh[4][16], a_ih[4][2];
  float bias[4][4], who[4];
#pragma unroll
  for (int m = 0; m < 4; ++m) {
    const int rowA = w * 64 + m * 16 + l16;                    // WG row = jl*4+gate
    const int grow = (rowA & 3) * 512 + jg * 64 + (rowA >> 2); // global gate row
#pragma unroll
    for (int kt = 0; kt < 16; ++kt) {
      const float* p = Whh + (size_t)grow * H_ + kt * 32 + lk * 8;
      short8 s;
#pragma unroll
      for (int e = 0; e < 8; ++e) s[e] = (short)f2bf_u(p[e]);
      a_hh[m][kt] = s;
    }
#pragma unroll
    for (int kt = 0; kt < 2; ++kt) {
      const float* p = Wih + (size_t)grow * I_ + kt * 32 + lk * 8;
      short8 s;
#pragma unroll
      for (int e = 0; e < 8; ++e) s[e] = (short)f2bf_u(p[e]);
      a_ih[m][kt] = s;
    }
    const int jm = jg * 64 + w * 16 + m * 4 + lk;
#pragma unroll
    for (int g = 0; g < 4; ++g) bias[m][g] = bih[g * 512 + jm] + bhh[g * 512 + jm];
    who[m] = Who[jm];
  }

  // LDS h-tile: [parity][plane][b][512 j], XOR-swizzled 16B granules (R10).
  __shared__ unsigned short hlds[2][2][16][512];   // 64 KiB
#define HOFS(pl, bb, kt) (((((pl) * 16 + (bb)) * 512) + (kt) * 32 + lk * 8) ^ (((bb) & 7) << 3))

  unsigned short* const hb0 = hbuf;
  unsigned short* const hb1 = hbuf + 2 * B_ * H_;
  const float* const xrow = x + (size_t)b * (T_ * I_);

  float c[4] = {0.f, 0.f, 0.f, 0.f};
  f32x4 xf0, xf1, xf2, xf3;
  {
    const float* xb = xrow + lk * 8;   // t = 0
    XLOADQ(xf0, xb, 0);   XLOADQ(xf1, xb, 16);
    XLOADQ(xf2, xb, 128); XLOADQ(xf3, xb, 144);
    WAITV(0);
  }

  for (int t = 0; t < T_; ++t) {
    const int pr = t & 1;
    const unsigned short* hp = pr ? hb1 : hb0;   // slot holding h(t-1)
    unsigned short* hn       = pr ? hb0 : hb1;   // slot for h(t)
    unsigned short* const hldsF = &hlds[pr][0][0][0];

    // x(t) regs ready: 4 oldest vmem ops are the x loads; up to 3 stores
    // from step t-1 (2 h publishes + 1 partial) may remain in flight.
    WAITV(3);

    f32x4 acc[4][2];
#pragma unroll
    for (int m = 0; m < 4; ++m) {
      acc[m][0] = (f32x4){0.f, 0.f, 0.f, 0.f};
      acc[m][1] = (f32x4){0.f, 0.f, 0.f, 0.f};
    }

    // ---- x projection from prefetched regs (pure VALU+MFMA) ----
#pragma unroll
    for (int kt = 0; kt < 2; ++kt) {
      f32x4 va = kt ? xf2 : xf0;
      f32x4 vb = kt ? xf3 : xf1;
      float v[8] = {va[0], va[1], va[2], va[3], vb[0], vb[1], vb[2], vb[3]};
      short8 xhi, xlo;
#pragma unroll
      for (int e = 0; e < 8; ++e) {
        unsigned hb = f2bf_u(v[e]);
        xhi[e] = (short)hb;
        xlo[e] = (short)f2bf_u(v[e] - bf2f(hb));
      }
#pragma unroll
      for (int m = 0; m < 4; ++m) {
        acc[m][0] = __builtin_amdgcn_mfma_f32_16x16x32_bf16(a_ih[m][kt], xhi, acc[m][0], 0, 0, 0);
        acc[m][1] = __builtin_amdgcn_mfma_f32_16x16x32_bf16(a_ih[m][kt], xlo, acc[m][1], 0, 0, 0);
      }
    }

    if (t > 0) {
      // ---- fused detect+load: poll this wave's tagged kt-quarter ----
      u32x4 qh[4], ql[4];
      const unsigned short* phh = hp + (size_t)b * H_ + w * 128 + lk * 8;
      const unsigned short* pll = phh + (size_t)(B_ * H_);
      const unsigned tlo = (unsigned)(t & 3);        // tag of h(t-1): epoch t&15
      const unsigned thi = (unsigned)((t >> 2) & 3);
      for (;;) {
        HLOADQ(qh[0], phh, 0);   HLOADQ(qh[1], phh, 64);
        HLOADQ(qh[2], phh, 128); HLOADQ(qh[3], phh, 192);
        HLOADQ(ql[0], pll, 0);   HLOADQ(ql[1], pll, 64);
        HLOADQ(ql[2], pll, 128); HLOADQ(ql[3], pll, 192);
        WAITV(0);
        unsigned bad = 0;
#pragma unroll
        for (int i = 0; i < 4; ++i) {
          bad |= (qh[i].x ^ tlo) | (qh[i].z ^ thi)
               | (ql[i].x ^ tlo) | (ql[i].z ^ thi);
        }
        bad &= 3u;
        if (__all(bad == 0)) break;
      }
      __builtin_amdgcn_fence(__ATOMIC_ACQUIRE, "workgroup");
      __builtin_amdgcn_sched_barrier(0);

      // ---- x(t+1) prefetch (drains during MFMA/pointwise) ----
      {
        const int tn = (t + 1 < T_) ? t + 1 : t;
        const float* xb = xrow + tn * I_ + lk * 8;
        XLOADQ(xf0, xb, 0);   XLOADQ(xf1, xb, 16);
        XLOADQ(xf2, xb, 128); XLOADQ(xf3, xb, 144);
      }

      // ---- stage into swizzled LDS ----
#pragma unroll
      for (int i = 0; i < 4; ++i) {
        *(u32x4*)&hldsF[HOFS(0, l16, 4 * w + i)] = qh[i];
        *(u32x4*)&hldsF[HOFS(1, l16, 4 * w + i)] = ql[i];
      }
      __syncthreads();

      // ---- h recurrence: fragments from LDS (compiler pipelines lgkmcnt) ----
#pragma unroll
      for (int kt = 0; kt < 16; ++kt) {
        short8 fh = *(const short8*)&hldsF[HOFS(0, l16, kt)];
        short8 fl = *(const short8*)&hldsF[HOFS(1, l16, kt)];
#pragma unroll
        for (int m = 0; m < 4; ++m) {
          acc[m][0] = __builtin_amdgcn_mfma_f32_16x16x32_bf16(a_hh[m][kt], fh, acc[m][0], 0, 0, 0);
          acc[m][1] = __builtin_amdgcn_mfma_f32_16x16x32_bf16(a_hh[m][kt], fl, acc[m][1], 0, 0, 0);
        }
      }
    } else {
      // t=0: no h term; just issue x(1) prefetch
      const float* xb = xrow + I_ + lk * 8;
      XLOADQ(xf0, xb, 0);   XLOADQ(xf1, xb, 16);
      XLOADQ(xf2, xb, 128); XLOADQ(xf3, xb, 144);
    }

    // ---- pointwise + pack; lane lk==0 injects epoch tags (R11-proven:
    //      pre-transpose wd[m] of lk==0 land at granule header words) ----
    const unsigned tgp = (unsigned)((t + 1) & 15);
    float p = 0.f;
    unsigned wd[4];           // packed (hi | lo<<16) per m
#pragma unroll
    for (int m = 0; m < 4; ++m) {
      float gi = sigm(acc[m][0].x + acc[m][1].x + bias[m][0]);
      float gf = sigm(acc[m][0].y + acc[m][1].y + bias[m][1]);
      float gg = tanh_(acc[m][0].z + acc[m][1].z + bias[m][2]);
      float go = sigm(acc[m][0].w + acc[m][1].w + bias[m][3]);
      c[m] = gf * c[m] + gi * gg;
      float hv = go * tanh_(c[m]);
      p += hv * who[m];
      unsigned tb = (m & 1) ? (tgp >> 2) : (tgp & 3u);
      unsigned hb = f2bf_u(hv);
      if (lk == 0) hb = (hb & ~3u) | tb;            // tagged hi
      unsigned lo = f2bf_u(hv - bf2f(hb));          // lo compensates hi tag
      if (lk == 0) lo = (lo & ~3u) | tb;            // tagged lo (2^-17|h|)
      wd[m] = hb | (lo << 16);
    }

    // ---- in-register 4x4 transpose across lk (lanes ^16, ^32) ----
    {
      unsigned r0[4], r1[4];
#pragma unroll
      for (int m = 0; m < 4; ++m) r0[m] = __shfl_xor(wd[m], 16);
#pragma unroll
      for (int m = 0; m < 4; ++m) if ((m ^ lk) & 1) wd[m] = r0[m ^ 1];
#pragma unroll
      for (int m = 0; m < 4; ++m) r1[m] = __shfl_xor(wd[m], 32);
#pragma unroll
      for (int m = 0; m < 4; ++m) if ((m ^ lk) & 2) wd[m] = r1[m ^ 2];
    }

    // ---- publish (fire-and-forget): tagged coalesced 8B stores ----
    {
      unsigned hi01 = (wd[0] & 0xffffu) | (wd[1] << 16);
      unsigned hi23 = (wd[2] & 0xffffu) | (wd[3] << 16);
      unsigned lo01 = (wd[0] >> 16) | (wd[1] & 0xffff0000u);
      unsigned lo23 = (wd[2] >> 16) | (wd[3] & 0xffff0000u);
      unsigned long long hiq = (unsigned long long)hi01 | ((unsigned long long)hi23 << 32);
      unsigned long long loq = (unsigned long long)lo01 | ((unsigned long long)lo23 << 32);
      unsigned short* ph = hn + (size_t)b * H_ + jg * 64 + w * 16 + lk * 4;
      HSTORED2(ph, hiq);
      HSTORED2(ph + B_ * H_, loq);
    }

    // ---- projection partial (fire-and-forget) ----
    p += __shfl_xor(p, 16);
    p += __shfl_xor(p, 32);          // sum over this wave's 16 j
    if (l < 16) {
      if constexpr (PLAIN != 0)
        part[(((size_t)jg * 4 + w) * B_ + b) * T_ + t] = p;
      else
        atomicAdd(part + ((size_t)jg * B_ + b) * T_ + t, p);
    }
  }
#undef HOFS
}

template <int NP>
__global__ __launch_bounds__(256) void reduce_out(const float* __restrict__ part,
                                                  const float* __restrict__ b_ho,
                                                  float* __restrict__ out) {
  int i = blockIdx.x * blockDim.x + threadIdx.x;
  if (i < B_ * T_) {
    float s = b_ho[0];
#pragma unroll
    for (int g = 0; g < NP; ++g) s += part[(size_t)g * B_ * T_ + i];
    out[i] = s;
  }
}

extern "C" void kernel_launch(void* const* d_in, const int* in_sizes, int n_in,
                              void* d_out, int out_size, void* d_ws, size_t ws_size,
                              hipStream_t stream) {
  (void)in_sizes; (void)n_in; (void)out_size;
  const float* x   = (const float*)d_in[0];
  const float* Wih = (const float*)d_in[1];
  const float* Whh = (const float*)d_in[2];
  const float* bih = (const float*)d_in[3];
  const float* bhh = (const float*)d_in[4];
  const float* Who = (const float*)d_in[5];
  const float* bho = (const float*)d_in[6];
  float* out = (float*)d_out;

  unsigned short* hbuf = (unsigned short*)d_ws;
  const size_t hbytes = (size_t)2 * 2 * B_ * H_ * sizeof(unsigned short);  // 512KB
  float* part = (float*)((char*)d_ws + hbytes);

  const size_t pbytes32 = (size_t)32 * B_ * T_ * sizeof(float);  // 8MB
  const size_t pbytes8  = (size_t)8 * B_ * T_ * sizeof(float);   // 2MB

  // hbuf needs NO init: epoch tags deterministically reject poison (0xAA ->
  // tag 2,2), zeros (0,0) and previous-replay end-state ((t-1)&15) at every t.

  if (ws_size >= hbytes + pbytes32) {
    lstm_kernel<1><<<dim3(64), dim3(256), 0, stream>>>(x, Wih, Whh, bih, bhh,
                                                       Who, part, hbuf);
    reduce_out<32><<<(B_ * T_ + 255) / 256, 256, 0, stream>>>(part, bho, out);
  } else {
    hipMemsetAsync(part, 0, pbytes8, stream);
    lstm_kernel<0><<<dim3(64), dim3(256), 0, stream>>>(x, Wih, Whh, bih, bhh,
                                                       Who, part, hbuf);
    reduce_out<8><<<(B_ * T_ + 255) / 256, 256, 0, stream>>>(part, bho, out);
  }
}

// Round 17
// 2219.015 us; speedup vs baseline: 2.4912x; 1.0123x over previous
//
#include <hip/hip_runtime.h>

// LSTM: B=128, T=512, I=64, H=512, O=1, fp32 in/out.
// R16 = R15 champion with ONE instruction-placement fix:
//   x(t+1) prefetch moved from BEFORE the LDS staging to AFTER the
//   __syncthreads. syncthreads emits s_waitcnt vmcnt(0) — issuing the
//   prefetch before it made the barrier drain a full x-load flight
//   (~500-900cy) every step. After the move, nothing is in vmem flight at
//   the barrier (poll's WAITV(0) drained h loads + leftover stores), and
//   the x flight hides under the 128-MFMA block.
// Core (R15-proven): NO ack, NO flags — tagged-granule fused detect+load;
// producer fire-and-forget publish; quarter-granularity poll; XOR-swizzled
// LDS staging; plain-store partials part[32][B][T].

#define B_ 128
#define T_ 512
#define I_ 64
#define H_ 512

typedef __attribute__((ext_vector_type(8))) short short8;   // 8 bf16
typedef __attribute__((ext_vector_type(4))) float f32x4;
typedef __attribute__((ext_vector_type(4))) unsigned u32x4;

__device__ inline unsigned f2bf_u(float f) {
  union { float f; unsigned u; } v; v.f = f;
  return (v.u + 0x7fffu + ((v.u >> 16) & 1u)) >> 16;  // RNE
}
__device__ inline float bf2f(unsigned s) {
  union { unsigned u; float f; } v; v.u = s << 16; return v.f;
}
__device__ inline float sigm(float x) { return 1.0f / (1.0f + __expf(-x)); }
__device__ inline float tanh_(float x) { return 1.0f - 2.0f / (1.0f + __expf(2.0f * x)); }

#define WAITV(N)                                        \
  asm volatile("s_waitcnt vmcnt(" #N ")" ::: "memory"); \
  __builtin_amdgcn_sched_barrier(0)

// coherent 16B load at L3 point
#define HLOADQ(dst, base, OFF)                                            \
  asm volatile("global_load_dwordx4 %0, %1, off offset:" #OFF " sc0 sc1"  \
               : "=v"(dst) : "v"(base))

// x: read-only input, normal cached path
#define XLOADQ(dst, base, OFF)                                            \
  asm volatile("global_load_dwordx4 %0, %1, off offset:" #OFF             \
               : "=v"(dst) : "v"(base))

// coherent 8B store at L3 point (4 lanes = contiguous 32B)
#define HSTORED2(base, v64)                                               \
  asm volatile("global_store_dwordx2 %0, %1, off sc0 sc1"                 \
               :: "v"(base), "v"(v64) : "memory")

template <int PLAIN>
__global__ __launch_bounds__(256, 1) void lstm_kernel(
    const float* __restrict__ x,    // [B,T,I]
    const float* __restrict__ Wih,  // [4H,I]
    const float* __restrict__ Whh,  // [4H,H]
    const float* __restrict__ bih,  // [4H]
    const float* __restrict__ bhh,  // [4H]
    const float* __restrict__ Who,  // [1,H]
    float* __restrict__ part,       // PLAIN: [32][B][T]; else [8][B][T] atomic
    unsigned short* __restrict__ hbuf)  // 2 bufs x (hi[B][H], lo[B][H]) bf16
{
  const int bid = blockIdx.x;
  const int jg = bid >> 3;      // 0..7  hidden group (64 j)
  const int bg = bid & 7;       // 0..7  batch group (16 b)
  const int tid = threadIdx.x;
  const int w = tid >> 6;       // wave 0..3
  const int l = tid & 63;
  const int l16 = l & 15;
  const int lk = l >> 4;        // 0..3
  const int b = bg * 16 + l16;

  // ---- resident weights: bf16 A-frags, 4 M-tiles/wave ----
  short8 a_hh[4][16], a_ih[4][2];
  float bias[4][4], who[4];
#pragma unroll
  for (int m = 0; m < 4; ++m) {
    const int rowA = w * 64 + m * 16 + l16;                    // WG row = jl*4+gate
    const int grow = (rowA & 3) * 512 + jg * 64 + (rowA >> 2); // global gate row
#pragma unroll
    for (int kt = 0; kt < 16; ++kt) {
      const float* p = Whh + (size_t)grow * H_ + kt * 32 + lk * 8;
      short8 s;
#pragma unroll
      for (int e = 0; e < 8; ++e) s[e] = (short)f2bf_u(p[e]);
      a_hh[m][kt] = s;
    }
#pragma unroll
    for (int kt = 0; kt < 2; ++kt) {
      const float* p = Wih + (size_t)grow * I_ + kt * 32 + lk * 8;
      short8 s;
#pragma unroll
      for (int e = 0; e < 8; ++e) s[e] = (short)f2bf_u(p[e]);
      a_ih[m][kt] = s;
    }
    const int jm = jg * 64 + w * 16 + m * 4 + lk;
#pragma unroll
    for (int g = 0; g < 4; ++g) bias[m][g] = bih[g * 512 + jm] + bhh[g * 512 + jm];
    who[m] = Who[jm];
  }

  // LDS h-tile: [parity][plane][b][512 j], XOR-swizzled 16B granules (R10).
  __shared__ unsigned short hlds[2][2][16][512];   // 64 KiB
#define HOFS(pl, bb, kt) (((((pl) * 16 + (bb)) * 512) + (kt) * 32 + lk * 8) ^ (((bb) & 7) << 3))

  unsigned short* const hb0 = hbuf;
  unsigned short* const hb1 = hbuf + 2 * B_ * H_;
  const float* const xrow = x + (size_t)b * (T_ * I_);

  float c[4] = {0.f, 0.f, 0.f, 0.f};
  f32x4 xf0, xf1, xf2, xf3;
  {
    const float* xb = xrow + lk * 8;   // t = 0
    XLOADQ(xf0, xb, 0);   XLOADQ(xf1, xb, 16);
    XLOADQ(xf2, xb, 128); XLOADQ(xf3, xb, 144);
    WAITV(0);
  }

  for (int t = 0; t < T_; ++t) {
    const int pr = t & 1;
    const unsigned short* hp = pr ? hb1 : hb0;   // slot holding h(t-1)
    unsigned short* hn       = pr ? hb0 : hb1;   // slot for h(t)
    unsigned short* const hldsF = &hlds[pr][0][0][0];

    // x(t) regs ready: 4 oldest vmem ops are the x loads; up to 3 stores
    // from step t-1 (2 h publishes + 1 partial) may remain in flight.
    WAITV(3);

    f32x4 acc[4][2];
#pragma unroll
    for (int m = 0; m < 4; ++m) {
      acc[m][0] = (f32x4){0.f, 0.f, 0.f, 0.f};
      acc[m][1] = (f32x4){0.f, 0.f, 0.f, 0.f};
    }

    // ---- x projection from prefetched regs (pure VALU+MFMA) ----
#pragma unroll
    for (int kt = 0; kt < 2; ++kt) {
      f32x4 va = kt ? xf2 : xf0;
      f32x4 vb = kt ? xf3 : xf1;
      float v[8] = {va[0], va[1], va[2], va[3], vb[0], vb[1], vb[2], vb[3]};
      short8 xhi, xlo;
#pragma unroll
      for (int e = 0; e < 8; ++e) {
        unsigned hb = f2bf_u(v[e]);
        xhi[e] = (short)hb;
        xlo[e] = (short)f2bf_u(v[e] - bf2f(hb));
      }
#pragma unroll
      for (int m = 0; m < 4; ++m) {
        acc[m][0] = __builtin_amdgcn_mfma_f32_16x16x32_bf16(a_ih[m][kt], xhi, acc[m][0], 0, 0, 0);
        acc[m][1] = __builtin_amdgcn_mfma_f32_16x16x32_bf16(a_ih[m][kt], xlo, acc[m][1], 0, 0, 0);
      }
    }

    if (t > 0) {
      // ---- fused detect+load: poll this wave's tagged kt-quarter ----
      u32x4 qh[4], ql[4];
      const unsigned short* phh = hp + (size_t)b * H_ + w * 128 + lk * 8;
      const unsigned short* pll = phh + (size_t)(B_ * H_);
      const unsigned tlo = (unsigned)(t & 3);        // tag of h(t-1): epoch t&15
      const unsigned thi = (unsigned)((t >> 2) & 3);
      for (;;) {
        HLOADQ(qh[0], phh, 0);   HLOADQ(qh[1], phh, 64);
        HLOADQ(qh[2], phh, 128); HLOADQ(qh[3], phh, 192);
        HLOADQ(ql[0], pll, 0);   HLOADQ(ql[1], pll, 64);
        HLOADQ(ql[2], pll, 128); HLOADQ(ql[3], pll, 192);
        WAITV(0);
        unsigned bad = 0;
#pragma unroll
        for (int i = 0; i < 4; ++i) {
          bad |= (qh[i].x ^ tlo) | (qh[i].z ^ thi)
               | (ql[i].x ^ tlo) | (ql[i].z ^ thi);
        }
        bad &= 3u;
        if (__all(bad == 0)) break;
      }
      __builtin_amdgcn_fence(__ATOMIC_ACQUIRE, "workgroup");
      __builtin_amdgcn_sched_barrier(0);

      // ---- stage into swizzled LDS (no x-prefetch in flight here) ----
#pragma unroll
      for (int i = 0; i < 4; ++i) {
        *(u32x4*)&hldsF[HOFS(0, l16, 4 * w + i)] = qh[i];
        *(u32x4*)&hldsF[HOFS(1, l16, 4 * w + i)] = ql[i];
      }
      __syncthreads();   // vmcnt already 0 -> barrier drains only LDS writes

      // ---- x(t+1) prefetch AFTER the barrier: flight hides under MFMA ----
      {
        const int tn = (t + 1 < T_) ? t + 1 : t;
        const float* xb = xrow + tn * I_ + lk * 8;
        XLOADQ(xf0, xb, 0);   XLOADQ(xf1, xb, 16);
        XLOADQ(xf2, xb, 128); XLOADQ(xf3, xb, 144);
      }

      // ---- h recurrence: fragments from LDS (compiler pipelines lgkmcnt) ----
#pragma unroll
      for (int kt = 0; kt < 16; ++kt) {
        short8 fh = *(const short8*)&hldsF[HOFS(0, l16, kt)];
        short8 fl = *(const short8*)&hldsF[HOFS(1, l16, kt)];
#pragma unroll
        for (int m = 0; m < 4; ++m) {
          acc[m][0] = __builtin_amdgcn_mfma_f32_16x16x32_bf16(a_hh[m][kt], fh, acc[m][0], 0, 0, 0);
          acc[m][1] = __builtin_amdgcn_mfma_f32_16x16x32_bf16(a_hh[m][kt], fl, acc[m][1], 0, 0, 0);
        }
      }
    } else {
      // t=0: no h term; just issue x(1) prefetch
      const float* xb = xrow + I_ + lk * 8;
      XLOADQ(xf0, xb, 0);   XLOADQ(xf1, xb, 16);
      XLOADQ(xf2, xb, 128); XLOADQ(xf3, xb, 144);
    }

    // ---- pointwise + pack; lane lk==0 injects epoch tags (R11-proven:
    //      pre-transpose wd[m] of lk==0 land at granule header words) ----
    const unsigned tgp = (unsigned)((t + 1) & 15);
    float p = 0.f;
    unsigned wd[4];           // packed (hi | lo<<16) per m
#pragma unroll
    for (int m = 0; m < 4; ++m) {
      float gi = sigm(acc[m][0].x + acc[m][1].x + bias[m][0]);
      float gf = sigm(acc[m][0].y + acc[m][1].y + bias[m][1]);
      float gg = tanh_(acc[m][0].z + acc[m][1].z + bias[m][2]);
      float go = sigm(acc[m][0].w + acc[m][1].w + bias[m][3]);
      c[m] = gf * c[m] + gi * gg;
      float hv = go * tanh_(c[m]);
      p += hv * who[m];
      unsigned tb = (m & 1) ? (tgp >> 2) : (tgp & 3u);
      unsigned hb = f2bf_u(hv);
      if (lk == 0) hb = (hb & ~3u) | tb;            // tagged hi
      unsigned lo = f2bf_u(hv - bf2f(hb));          // lo compensates hi tag
      if (lk == 0) lo = (lo & ~3u) | tb;            // tagged lo (2^-17|h|)
      wd[m] = hb | (lo << 16);
    }

    // ---- in-register 4x4 transpose across lk (lanes ^16, ^32) ----
    {
      unsigned r0[4], r1[4];
#pragma unroll
      for (int m = 0; m < 4; ++m) r0[m] = __shfl_xor(wd[m], 16);
#pragma unroll
      for (int m = 0; m < 4; ++m) if ((m ^ lk) & 1) wd[m] = r0[m ^ 1];
#pragma unroll
      for (int m = 0; m < 4; ++m) r1[m] = __shfl_xor(wd[m], 32);
#pragma unroll
      for (int m = 0; m < 4; ++m) if ((m ^ lk) & 2) wd[m] = r1[m ^ 2];
    }

    // ---- publish (fire-and-forget): tagged coalesced 8B stores ----
    {
      unsigned hi01 = (wd[0] & 0xffffu) | (wd[1] << 16);
      unsigned hi23 = (wd[2] & 0xffffu) | (wd[3] << 16);
      unsigned lo01 = (wd[0] >> 16) | (wd[1] & 0xffff0000u);
      unsigned lo23 = (wd[2] >> 16) | (wd[3] & 0xffff0000u);
      unsigned long long hiq = (unsigned long long)hi01 | ((unsigned long long)hi23 << 32);
      unsigned long long loq = (unsigned long long)lo01 | ((unsigned long long)lo23 << 32);
      unsigned short* ph = hn + (size_t)b * H_ + jg * 64 + w * 16 + lk * 4;
      HSTORED2(ph, hiq);
      HSTORED2(ph + B_ * H_, loq);
    }

    // ---- projection partial (fire-and-forget) ----
    p += __shfl_xor(p, 16);
    p += __shfl_xor(p, 32);          // sum over this wave's 16 j
    if (l < 16) {
      if constexpr (PLAIN != 0)
        part[(((size_t)jg * 4 + w) * B_ + b) * T_ + t] = p;
      else
        atomicAdd(part + ((size_t)jg * B_ + b) * T_ + t, p);
    }
  }
#undef HOFS
}

template <int NP>
__global__ __launch_bounds__(256) void reduce_out(const float* __restrict__ part,
                                                  const float* __restrict__ b_ho,
                                                  float* __restrict__ out) {
  int i = blockIdx.x * blockDim.x + threadIdx.x;
  if (i < B_ * T_) {
    float s = b_ho[0];
#pragma unroll
    for (int g = 0; g < NP; ++g) s += part[(size_t)g * B_ * T_ + i];
    out[i] = s;
  }
}

extern "C" void kernel_launch(void* const* d_in, const int* in_sizes, int n_in,
                              void* d_out, int out_size, void* d_ws, size_t ws_size,
                              hipStream_t stream) {
  (void)in_sizes; (void)n_in; (void)out_size;
  const float* x   = (const float*)d_in[0];
  const float* Wih = (const float*)d_in[1];
  const float* Whh = (const float*)d_in[2];
  const float* bih = (const float*)d_in[3];
  const float* bhh = (const float*)d_in[4];
  const float* Who = (const float*)d_in[5];
  const float* bho = (const float*)d_in[6];
  float* out = (float*)d_out;

  unsigned short* hbuf = (unsigned short*)d_ws;
  const size_t hbytes = (size_t)2 * 2 * B_ * H_ * sizeof(unsigned short);  // 512KB
  float* part = (float*)((char*)d_ws + hbytes);

  const size_t pbytes32 = (size_t)32 * B_ * T_ * sizeof(float);  // 8MB
  const size_t pbytes8  = (size_t)8 * B_ * T_ * sizeof(float);   // 2MB

  // hbuf needs NO init: epoch tags deterministically reject poison (0xAA ->
  // tag 2,2), zeros (0,0) and previous-replay end-state ((t-1)&15) at every t.

  if (ws_size >= hbytes + pbytes32) {
    lstm_kernel<1><<<dim3(64), dim3(256), 0, stream>>>(x, Wih, Whh, bih, bhh,
                                                       Who, part, hbuf);
    reduce_out<32><<<(B_ * T_ + 255) / 256, 256, 0, stream>>>(part, bho, out);
  } else {
    hipMemsetAsync(part, 0, pbytes8, stream);
    lstm_kernel<0><<<dim3(64), dim3(256), 0, stream>>>(x, Wih, Whh, bih, bhh,
                                                       Who, part, hbuf);
    reduce_out<8><<<(B_ * T_ + 255) / 256, 256, 0, stream>>>(part, bho, out);
  }
}